// Round 8
// baseline (176.503 us; speedup 1.0000x reference)
//
#include <hip/hip_runtime.h>
#include <hip/hip_fp16.h>

#define CC 256   // input channels
#define OO 256   // output channels
#define HH 64
#define WW 64
#define HWN 4096 // H*W
#define MPB 64   // pixels per block
#define NPB 128  // outputs per block
#define KCH 128  // c-chunk for weight staging

typedef _Float16 half8 __attribute__((ext_vector_type(8)));
typedef _Float16 half2v __attribute__((ext_vector_type(2)));
typedef float f32x4 __attribute__((ext_vector_type(4)));

__device__ __forceinline__ half2v u2h(unsigned u) {
  half2v h; __builtin_memcpy(&h, &u, 4); return h;
}
__device__ __forceinline__ unsigned h2u(half2v h) {
  unsigned u; __builtin_memcpy(&u, &h, 4); return u;
}
__device__ __forceinline__ unsigned short f2h(float f) {
  _Float16 h = (_Float16)f;
  unsigned short us; __builtin_memcpy(&us, &h, 2);
  return us;
}
__device__ __forceinline__ unsigned dupu(unsigned short us) {
  return ((unsigned)us << 16) | us;
}
__device__ __forceinline__ unsigned pk2(float a, float b) {
  half2v h = {(_Float16)a, (_Float16)b};
  return h2u(h);
}

// ---------- fused prep: x [N,C,H,W] f32 -> xt [N,HW,C] fp16 ; w -> wt [9][O][C] fp16 ----------
__global__ __launch_bounds__(256) void prep_kernel(
    const float* __restrict__ x, const float* __restrict__ w,
    _Float16* __restrict__ xt, _Float16* __restrict__ wt) {
  __shared__ float tile[64][65];
  const int bid = blockIdx.x;
  const int tid = threadIdx.x;
  if (bid < 1024) {
    const int n  = bid >> 8;
    const int c0 = ((bid >> 6) & 3) * 64;
    const int s0 = (bid & 63) * 64;
    {
      int r  = tid >> 2;
      int sc = (tid & 3) * 16;
      const float* xp = x + ((size_t)(n * CC + c0 + r)) * HWN + s0 + sc;
      *(float4*)&tile[r][sc]      = *(const float4*)(xp);
      *(float4*)&tile[r][sc + 4]  = *(const float4*)(xp + 4);
      *(float4*)&tile[r][sc + 8]  = *(const float4*)(xp + 8);
      *(float4*)&tile[r][sc + 12] = *(const float4*)(xp + 12);
    }
    __syncthreads();
    {
      int s  = tid >> 2;
      int cg = (tid & 3) * 16;
      uint4 u0, u1;
      u0.x = pk2(tile[cg + 0][s],  tile[cg + 1][s]);
      u0.y = pk2(tile[cg + 2][s],  tile[cg + 3][s]);
      u0.z = pk2(tile[cg + 4][s],  tile[cg + 5][s]);
      u0.w = pk2(tile[cg + 6][s],  tile[cg + 7][s]);
      u1.x = pk2(tile[cg + 8][s],  tile[cg + 9][s]);
      u1.y = pk2(tile[cg + 10][s], tile[cg + 11][s]);
      u1.z = pk2(tile[cg + 12][s], tile[cg + 13][s]);
      u1.w = pk2(tile[cg + 14][s], tile[cg + 15][s]);
      _Float16* op = xt + ((size_t)(n * HWN + s0 + s)) * CC + c0 + cg;
      *(uint4*)(op)     = u0;
      *(uint4*)(op + 8) = u1;
    }
  } else {
    int e = (bid - 1024) * 256 + tid;   // 0 .. 589823
    int k = e >> 16;
    int o = (e >> 8) & 255;
    int c = e & 255;
    wt[e] = (_Float16)w[((size_t)o * CC + c) * 9 + k];
  }
}

// ---------------- fused deform-sample (fp16 packed) + MFMA GEMM ----------------
// grid 512 x 256 thr. Block: 64 px x 128 o. XCD-aware decode (XCD ~ bx%8):
//   nb = (bx&7)>>1 (one image per XCD), o-half = bx&1, pixel group = bx>>3.
// LDS layouts are MFMA-fragment-contiguous: frag = 512 halfs, lane L at L*8.
//   val_lds frag (g*4 + mt): A[m=mt*16+(L&15)][c=g*32+(L>>4)*8+j]
//   w_lds  frag (ot*4 + ks): B[o=ot*16+(L&15)][c=cc*128+ks*32+(L>>4)*8+j]
// -> every ds_read/ds_write is lane-linear b128: zero bank conflicts (R4-proven).
__global__ __launch_bounds__(256, 2) void deform_mfma_kernel(
    const _Float16* __restrict__ xt,   // [4][4096][256] fp16
    const _Float16* __restrict__ wt,   // [9][256][256] fp16 ([k][o][c])
    const float* __restrict__ off,
    float* __restrict__ out) {
  __shared__ __align__(16) _Float16 val_lds[32 * 512];   // 32 KB
  __shared__ __align__(16) _Float16 w_lds[32 * 512];     // 32 KB
  __shared__ ushort4 s_po[MPB * 9];   // clamped flat corner row offsets
  __shared__ ushort4 s_pw[MPB * 9];   // fp16 bilinear weights

  const int tid  = threadIdx.x;
  const int lane = tid & 63;
  const int wv   = tid >> 6;
  const int n15  = lane & 15;
  const int quad = lane >> 4;

  const int bx    = blockIdx.x;
  const int nb    = (bx & 7) >> 1;          // image: constant per XCD
  const int hw0   = (bx >> 3) * MPB;        // pixel group within image
  const int obase = (bx & 1) * NPB;         // output half

  // ---- precompute per-(pixel,tap) sampling params ----
  for (int e = tid; e < MPB * 9; e += 256) {
    int p = e / 9;
    int k = e - p * 9;
    int hw = hw0 + p;
    int h = hw >> 6, w = hw & 63;
    size_t ob = ((size_t)(nb * HWN + hw)) * 18 + 2 * k;
    float2 d = *(const float2*)(off + ob);
    float py = (float)(h + k / 3 - 1) + d.x;
    float px = (float)(w + k % 3 - 1) + d.y;
    float fy = floorf(py), fx = floorf(px);
    int iy = (int)fy, ix = (int)fx;
    float wy = py - fy, wx = px - fx;
    float my0 = ((unsigned)iy       < (unsigned)HH) ? 1.f : 0.f;
    float my1 = ((unsigned)(iy + 1) < (unsigned)HH) ? 1.f : 0.f;
    float mx0 = ((unsigned)ix       < (unsigned)WW) ? 1.f : 0.f;
    float mx1 = ((unsigned)(ix + 1) < (unsigned)WW) ? 1.f : 0.f;
    int iy0 = min(max(iy, 0), HH - 1), iy1 = min(max(iy + 1, 0), HH - 1);
    int ix0 = min(max(ix, 0), WW - 1), ix1 = min(max(ix + 1, 0), WW - 1);
    s_po[e] = make_ushort4((unsigned short)(iy0 * WW + ix0),
                           (unsigned short)(iy0 * WW + ix1),
                           (unsigned short)(iy1 * WW + ix0),
                           (unsigned short)(iy1 * WW + ix1));
    s_pw[e] = make_ushort4(f2h((1.f - wy) * (1.f - wx) * my0 * mx0),
                           f2h((1.f - wy) * wx         * my0 * mx1),
                           f2h(wy         * (1.f - wx) * my1 * mx0),
                           f2h(wy         * wx         * my1 * mx1));
  }

  f32x4 acc[4][2];
#pragma unroll
  for (int a = 0; a < 4; ++a)
#pragma unroll
    for (int b = 0; b < 2; ++b) acc[a][b] = (f32x4){0.f, 0.f, 0.f, 0.f};

  const _Float16* xb = xt + (size_t)nb * HWN * CC;
  const int p = wv * 16 + n15;   // this thread's pixel (m-tile = wv)

  for (int k = 0; k < 9; ++k) {
    __syncthreads();   // prev tap A-reads done; (k==0) params visible

    // ---- sample tap k: pixel p, channels quad*8 + g*32; frag-linear LDS writes ----
    {
      int idx = p * 9 + k;
      ushort4 o4 = s_po[idx];
      ushort4 hw4 = s_pw[idx];
      half2v w00 = u2h(dupu(hw4.x)), w01 = u2h(dupu(hw4.y));
      half2v w10 = u2h(dupu(hw4.z)), w11 = u2h(dupu(hw4.w));
      const _Float16* p00 = xb + (size_t)o4.x * CC + quad * 8;
      const _Float16* p01 = xb + (size_t)o4.y * CC + quad * 8;
      const _Float16* p10 = xb + (size_t)o4.z * CC + quad * 8;
      const _Float16* p11 = xb + (size_t)o4.w * CC + quad * 8;
#pragma unroll
      for (int g = 0; g < 8; ++g) {
        uint4 v00 = *(const uint4*)(p00 + g * 32);
        uint4 v01 = *(const uint4*)(p01 + g * 32);
        uint4 v10 = *(const uint4*)(p10 + g * 32);
        uint4 v11 = *(const uint4*)(p11 + g * 32);
        uint4 r;
        r.x = h2u(u2h(v00.x) * w00 + u2h(v01.x) * w01 + u2h(v10.x) * w10 + u2h(v11.x) * w11);
        r.y = h2u(u2h(v00.y) * w00 + u2h(v01.y) * w01 + u2h(v10.y) * w10 + u2h(v11.y) * w11);
        r.z = h2u(u2h(v00.z) * w00 + u2h(v01.z) * w01 + u2h(v10.z) * w10 + u2h(v11.z) * w11);
        r.w = h2u(u2h(v00.w) * w00 + u2h(v01.w) * w01 + u2h(v10.w) * w10 + u2h(v11.w) * w11);
        *(uint4*)(val_lds + (g * 4 + wv) * 512 + lane * 8) = r;   // lane-linear b128
      }
    }

    // ---- GEMM tap k over two 128-channel chunks ----
    const _Float16* wkb = wt + ((size_t)(k * OO + obase)) * CC;
    for (int cc = 0; cc < CC / KCH; ++cc) {
      __syncthreads();   // prev chunk B-reads done
      // stage 128 o x 128 c into B-frag layout: wave wv owns frags wv*8..wv*8+7
#pragma unroll
      for (int fi = 0; fi < 8; ++fi) {
        int fb = wv * 8 + fi;
        int ot = fb >> 2, ks = fb & 3;
        const uint4* src = (const uint4*)(wkb + ((size_t)(ot * 16 + n15)) * CC +
                                          cc * KCH + ks * 32 + quad * 8);
        *(uint4*)(w_lds + fb * 512 + lane * 8) = *src;   // lane-linear b128
      }
      __syncthreads();   // w_lds staged; also orders val_lds writes before A-reads (cc==0)
#pragma unroll
      for (int ks = 0; ks < 4; ++ks) {
        half8 afr[4], bfr[2];
#pragma unroll
        for (int mt = 0; mt < 4; ++mt)
          afr[mt] = *(const half8*)(val_lds + ((cc * 4 + ks) * 4 + mt) * 512 + lane * 8);
#pragma unroll
        for (int nt = 0; nt < 2; ++nt)
          bfr[nt] = *(const half8*)(w_lds + ((wv * 2 + nt) * 4 + ks) * 512 + lane * 8);
#pragma unroll
        for (int mt = 0; mt < 4; ++mt)
#pragma unroll
          for (int nt = 0; nt < 2; ++nt)
            acc[mt][nt] = __builtin_amdgcn_mfma_f32_16x16x32_f16(
                afr[mt], bfr[nt], acc[mt][nt], 0, 0, 0);
      }
    }
  }

  // ---- epilogue: D: col=lane&15 -> o, row=quad*4+reg -> pixel ----
#pragma unroll
  for (int mt = 0; mt < 4; ++mt)
#pragma unroll
    for (int nt = 0; nt < 2; ++nt) {
      int o  = obase + wv * 32 + nt * 16 + n15;
      int px = hw0 + mt * 16 + quad * 4;
      *(f32x4*)(out + ((size_t)nb * OO + o) * HWN + px) = acc[mt][nt];
    }
}

extern "C" void kernel_launch(void* const* d_in, const int* in_sizes, int n_in,
                              void* d_out, int out_size, void* d_ws, size_t ws_size,
                              hipStream_t stream) {
  const float* x   = (const float*)d_in[0];   // [4,256,64,64]
  const float* off = (const float*)d_in[1];   // [4,4096,18]
  const float* w   = (const float*)d_in[2];   // [256,256,3,3]
  float* out = (float*)d_out;                 // [4,256,64,64]

  _Float16* wt = (_Float16*)d_ws;             // 589824 fp16
  _Float16* xt = wt + 589824;                 // 4194304 fp16

  prep_kernel<<<1024 + 2304, 256, 0, stream>>>(x, w, xt, wt);
  deform_mfma_kernel<<<(4 * HWN / MPB) * (OO / NPB), 256, 0, stream>>>(xt, wt, off, out);
}